// Round 9
// baseline (806.430 us; speedup 1.0000x reference)
//
#include <hip/hip_runtime.h>
#include <math.h>

static constexpr int H = 256, W = 256, HW = H * W;

typedef __attribute__((ext_vector_type(8))) _Float16 half8v;  // 16B
typedef __attribute__((ext_vector_type(4))) _Float16 half4v;  // 8B
typedef __attribute__((ext_vector_type(4))) float  float4v;   // MFMA acc

// ---------- activations ----------
__device__ __forceinline__ float gelu_f(float v) {
  return 0.5f * v * (1.0f + erff(v * 0.70710678118654752440f));
}
template<int ACT>
__device__ __forceinline__ float apply_act(float v) {
  if constexpr (ACT == 1) return v >= 0.f ? v : 0.1f * v;   // LeakyReLU(0.1)
  if constexpr (ACT == 2) return gelu_f(v);
  return v;
}

// ---------- pack: NCHW f32 (C=32) -> chunked NHWC f16 hi + scaled lo ----------
template<int C>
__global__ __launch_bounds__(256)
void pack_k(const float* __restrict__ in, _Float16* __restrict__ hi, _Float16* __restrict__ lo)
{
  const int p = blockIdx.x * 256 + threadIdx.x;
  const int b = blockIdx.y;
  const float* ip = in + (size_t)b * C * HW + p;
  __attribute__((aligned(16))) _Float16 hv[C], lv[C];
  #pragma unroll
  for (int c = 0; c < C; ++c) {
    float v = ip[(size_t)c * HW];
    _Float16 h = (_Float16)v;
    hv[c] = h;
    lv[c] = (_Float16)((v - (float)h) * 2048.0f);
  }
  size_t ob = ((size_t)b * HW + p) * C;
  #pragma unroll
  for (int j = 0; j < C / 8; ++j) {
    *(half8v*)&hi[ob + j * 8] = *(half8v*)&hv[j * 8];
    *(half8v*)&lo[ob + j * 8] = *(half8v*)&lv[j * 8];
  }
}

// ---------- weight prep: [OC][CIN][3][3] f32 -> [tap][OC][CIN] f16 hi + scaled lo ----------
__global__ __launch_bounds__(256)
void prep_w_k(const float* __restrict__ w, _Float16* __restrict__ hi,
              _Float16* __restrict__ lo, int OC, int CIN)
{
  int tid = blockIdx.x * 256 + threadIdx.x;
  if (tid >= OC * CIN * 9) return;
  int ci = tid % CIN; int r = tid / CIN; int oc = r % OC; int tap = r / OC;
  float v = w[((size_t)oc * CIN + ci) * 9 + tap];
  _Float16 h = (_Float16)v;
  hi[tid] = h;
  lo[tid] = (_Float16)((v - (float)h) * 2048.0f);
}

// ---------- 3x3 conv, f16 MFMA split-3; chunked-NHWC input; T14 staged pipeline ----------
// OMODE: 0 = NCHW f32 out, 1 = NHWC f16 hi/lo out (OC=32), 2 = NHWC f32 out.
// 1-D grid, XCD-grouped decode: xcd=bid&7, q=bid>>3, ocg=q%nOc, tile=(q/nOc)*8+xcd
//   -> all oc-groups of a tile land on ONE XCD at adjacent slots (L2 reuse),
//      consecutive tiles are y-adjacent (halo reuse). Bijective (total%8==0).
// Per cc-chunk: issue 8 of 15 next-chunk loads to regs BEFORE the tap loop
// (latency hides under ~4000cy of MFMA), load remaining 7 + ds_write all in the
// write phase between barriers (residual stall covered by co-resident blocks).
template<int CIN, int OC, int ACT, int OMODE>
__global__ __launch_bounds__(256)
void conv3x3_mfma_k(const _Float16* __restrict__ iH0, const _Float16* __restrict__ iL0,
                    const _Float16* __restrict__ iH1, const _Float16* __restrict__ iL1, int cin0,
                    const _Float16* __restrict__ wHi, const _Float16* __restrict__ wLo,
                    const float* __restrict__ bias,
                    float* __restrict__ outF, _Float16* __restrict__ oH, _Float16* __restrict__ oL)
{
  constexpr int nOc = OC / 32;
  __shared__ _Float16 sB[6 * 66 * 64];   // 50,688 B -> 3 blocks/CU

  const int l  = threadIdx.x & 63;
  const int wv = threadIdx.x >> 6;

  const int bid = blockIdx.x;
  const int xcd = bid & 7, q = bid >> 3;
  const int ocg  = q % nOc;
  const int tIdx = (q / nOc) * 8 + xcd;
  const int b   = tIdx >> 8;
  const int x0  = ((tIdx >> 6) & 3) * 64;
  const int y0  = (tIdx & 63) * 4;
  const int oc0 = ocg * 32;

  float4v accP[2][4], accQ[2][4];
  #pragma unroll
  for (int of = 0; of < 2; ++of)
    #pragma unroll
    for (int f = 0; f < 4; ++f) {
      accP[of][f] = (float4v){0.f, 0.f, 0.f, 0.f};
      accQ[of][f] = (float4v){0.f, 0.f, 0.f, 0.f};
    }

  const int k8  = (l >> 4) * 8;
  const int ocl = l & 15;
  const int sq  = l & 3;          // ci granule
  const int spx = l >> 2;         // px offset within 16-px subtile

  // per-task address calc (i compile-time via unroll; r/s/bsel are wave-uniform SALU)
  auto taskAddr = [&](int i, int& gOff, int& ldsOff, int& bsel) {
    int t = wv + 4 * i;
    int r = t / 10, rem = t - r * 10;
    bsel = rem / 5; int s = rem - bsel * 5;
    int gy = y0 + r - 1;
    bool vy = (gy >= 0) && (gy < H);
    int gyc = gy < 0 ? 0 : (gy >= H ? H - 1 : gy);
    int pxl = s * 16 + spx;                  // s=4: px 64,65 (lanes 0-7 only)
    bool lact = (s < 4) || (l < 8);
    int gx = x0 + pxl - 1;
    bool vx = (gx >= 0) && (gx < W);
    int gxc = gx < 0 ? 0 : (gx >= W ? W - 1 : gx);
    int cls = (sq + bsel * 4) ^ (pxl & 7);
    gOff   = (lact && vy && vx) ? ((gyc * W + gxc) * 32 + sq * 8) : -1;
    ldsOff = lact ? ((r * 66 + pxl) * 64 + cls * 8) : -1;
  };
  auto chunkBase = [&](int cc, const _Float16*& cbH, const _Float16*& cbL) {
    if (cc < cin0) {
      size_t o = (size_t)(b * (cin0 >> 5) + (cc >> 5)) * HW * 32;
      cbH = iH0 + o; cbL = iL0 + o;
    } else {
      size_t o = (size_t)(b * ((CIN - cin0) >> 5) + ((cc - cin0) >> 5)) * HW * 32;
      cbH = iH1 + o; cbL = iL1 + o;
    }
  };

  half8v p[15];
  auto loadRange = [&](int loI, int hiI, const _Float16* cbH, const _Float16* cbL) {
    #pragma unroll
    for (int i = 0; i < 15; ++i) if (i >= loI && i < hiI) {
      int gOff, ldsOff, bsel;
      taskAddr(i, gOff, ldsOff, bsel);
      const _Float16* src = bsel ? cbL : cbH;
      half8v v;
      #pragma unroll
      for (int k = 0; k < 8; ++k) v[k] = (_Float16)0;
      if (gOff >= 0) v = *(const half8v*)&src[gOff];
      p[i] = v;
    }
  };
  auto writeAll = [&]() {
    #pragma unroll
    for (int i = 0; i < 15; ++i) {
      int gOff, ldsOff, bsel;
      taskAddr(i, gOff, ldsOff, bsel);
      if (ldsOff >= 0) *(half8v*)&sB[ldsOff] = p[i];
    }
  };

  // prologue: stage chunk 0
  {
    const _Float16 *c0H, *c0L;
    chunkBase(0, c0H, c0L);
    loadRange(0, 15, c0H, c0L);
  }
  writeAll();
  __syncthreads();

  #pragma unroll 1
  for (int cc = 0; cc < CIN; cc += 32) {
    const _Float16 *nH = nullptr, *nL = nullptr;
    const bool hasNext = (cc + 32 < CIN);
    if (hasNext) {
      chunkBase(cc + 32, nH, nL);
      loadRange(0, 8, nH, nL);               // issue early: hides under tap loop
    }

    #pragma unroll 1
    for (int tap = 0; tap < 9; ++tap) {
      const int dy = tap / 3, dx = tap - 3 * (tap / 3);
      const _Float16* hp = wHi + ((size_t)tap * OC + oc0 + ocl) * CIN + cc + k8;
      const _Float16* lp = wLo + ((size_t)tap * OC + oc0 + ocl) * CIN + cc + k8;
      half8v ah0 = *(const half8v*)hp;
      half8v ah1 = *(const half8v*)(hp + (size_t)16 * CIN);
      half8v aq0 = *(const half8v*)lp;
      half8v aq1 = *(const half8v*)(lp + (size_t)16 * CIN);
      const int px = ocl + dx;
      const int rbase = ((wv + dy) * 66 + px) * 64;
      const int clsH = (l >> 4) ^ (px & 7);
      const int clsQ = ((l >> 4) + 4) ^ (px & 7);
      #pragma unroll
      for (int f = 0; f < 4; ++f) {
        half8v bh = *(const half8v*)&sB[rbase + f * 1024 + clsH * 8];
        half8v bq = *(const half8v*)&sB[rbase + f * 1024 + clsQ * 8];
        accP[0][f] = __builtin_amdgcn_mfma_f32_16x16x32_f16(ah0, bh, accP[0][f], 0, 0, 0);
        accQ[0][f] = __builtin_amdgcn_mfma_f32_16x16x32_f16(ah0, bq, accQ[0][f], 0, 0, 0);
        accQ[0][f] = __builtin_amdgcn_mfma_f32_16x16x32_f16(aq0, bh, accQ[0][f], 0, 0, 0);
        accP[1][f] = __builtin_amdgcn_mfma_f32_16x16x32_f16(ah1, bh, accP[1][f], 0, 0, 0);
        accQ[1][f] = __builtin_amdgcn_mfma_f32_16x16x32_f16(ah1, bq, accQ[1][f], 0, 0, 0);
        accQ[1][f] = __builtin_amdgcn_mfma_f32_16x16x32_f16(aq1, bh, accQ[1][f], 0, 0, 0);
      }
    }

    if (hasNext) {
      __syncthreads();                        // readers done with sB
      loadRange(8, 15, nH, nL);               // remaining 7 (short stall, covered)
      writeAll();
      __syncthreads();                        // sB(next) ready
    }
  }

  // ---- epilogue: D col=l&15 (px), row=(l>>4)*4+reg (oc) ----
  #pragma unroll
  for (int of = 0; of < 2; ++of)
    #pragma unroll
    for (int f = 0; f < 4; ++f) {
      const int px  = x0 + f * 16 + ocl;
      const int occ = oc0 + of * 16 + (l >> 4) * 4;
      if constexpr (OMODE == 0) {
        #pragma unroll
        for (int r = 0; r < 4; ++r) {
          float bv = bias ? bias[occ + r] : 0.f;
          float vv = accP[of][f][r] + accQ[of][f][r] * (1.0f / 2048.0f) + bv;
          outF[((size_t)(b * OC + occ + r) * H + (y0 + wv)) * W + px] = apply_act<ACT>(vv);
        }
      } else if constexpr (OMODE == 1) {
        __attribute__((aligned(8))) _Float16 hv[4], lv[4];
        #pragma unroll
        for (int r = 0; r < 4; ++r) {
          float bv = bias ? bias[occ + r] : 0.f;
          float vv = apply_act<ACT>(accP[of][f][r] + accQ[of][f][r] * (1.0f / 2048.0f) + bv);
          _Float16 h = (_Float16)vv;
          hv[r] = h;
          lv[r] = (_Float16)((vv - (float)h) * 2048.0f);
        }
        size_t ob = ((size_t)b * HW + (size_t)(y0 + wv) * W + px) * OC + occ;
        *(half4v*)&oH[ob] = *(half4v*)&hv[0];
        *(half4v*)&oL[ob] = *(half4v*)&lv[0];
      } else {
        float4 v4;
        #pragma unroll
        for (int r = 0; r < 4; ++r) {
          float bv = bias ? bias[occ + r] : 0.f;
          ((float*)&v4)[r] = apply_act<ACT>(accP[of][f][r] + accQ[of][f][r] * (1.0f / 2048.0f) + bv);
        }
        *(float4*)&outF[((size_t)b * HW + (size_t)(y0 + wv) * W + px) * OC + occ] = v4;
      }
    }
}

// ---------- 1x1 conv: NHWC f32 in -> chunked NHWC f16 hi/lo out ----------
template<int CIN, int OCB, int ACT>
__global__ __launch_bounds__(256)
void conv1x1_nhwc_k(const float* __restrict__ in, const float* __restrict__ w,
                    _Float16* __restrict__ oH, _Float16* __restrict__ oL, int OC)
{
  __shared__ __align__(16) float sW[OCB][CIN];
  const int b   = blockIdx.y;
  const int oc0 = blockIdx.z * OCB;
  for (int t = threadIdx.x; t < OCB * CIN; t += 256)
    sW[t / CIN][t % CIN] = w[(size_t)(oc0 + t / CIN) * CIN + (t % CIN)];
  __syncthreads();

  const int pb = blockIdx.x * 1024 + threadIdx.x;    // 4 px at stride 256
  float acc[OCB][4];
  #pragma unroll
  for (int o = 0; o < OCB; ++o)
    #pragma unroll
    for (int i = 0; i < 4; ++i) acc[o][i] = 0.f;

  #pragma unroll 1
  for (int c0 = 0; c0 < CIN; c0 += 8) {
    float v[4][8];
    #pragma unroll
    for (int i = 0; i < 4; ++i) {
      const float* ip = in + ((size_t)b * HW + pb + i * 256) * CIN + c0;
      float4 a = *(const float4*)ip;
      float4 c = *(const float4*)(ip + 4);
      v[i][0]=a.x; v[i][1]=a.y; v[i][2]=a.z; v[i][3]=a.w;
      v[i][4]=c.x; v[i][5]=c.y; v[i][6]=c.z; v[i][7]=c.w;
    }
    #pragma unroll
    for (int o = 0; o < OCB; ++o) {
      const float4 w0 = *(const float4*)&sW[o][c0];
      const float4 w1 = *(const float4*)&sW[o][c0 + 4];
      #pragma unroll
      for (int i = 0; i < 4; ++i) {
        acc[o][i] += v[i][0]*w0.x + v[i][1]*w0.y + v[i][2]*w0.z + v[i][3]*w0.w
                   + v[i][4]*w1.x + v[i][5]*w1.y + v[i][6]*w1.z + v[i][7]*w1.w;
      }
    }
  }
  #pragma unroll
  for (int i = 0; i < 4; ++i) {
    __attribute__((aligned(16))) _Float16 hv[OCB], lv[OCB];
    #pragma unroll
    for (int o = 0; o < OCB; ++o) {
      float vv = apply_act<ACT>(acc[o][i]);
      _Float16 h = (_Float16)vv;
      hv[o] = h;
      lv[o] = (_Float16)((vv - (float)h) * 2048.0f);
    }
    // chunked store: [B][OC/32][HW][32]
    size_t ob = ((size_t)(b * (OC >> 5) + (oc0 >> 5)) * HW + pb + i * 256) * 32 + (oc0 & 31);
    #pragma unroll
    for (int j = 0; j < OCB / 8; ++j) {
      *(half8v*)&oH[ob + j * 8] = *(half8v*)&hv[j * 8];
      *(half8v*)&oL[ob + j * 8] = *(half8v*)&lv[j * 8];
    }
  }
}

// ---------- corr + top-3 (jax tie-break: lower index wins); warp NCHW f32 ----------
__global__ __launch_bounds__(256)
void corr_topk_k(const float* __restrict__ warp, const float* __restrict__ x,
                 int* __restrict__ idxo)
{
  const int p = blockIdx.x * 256 + threadIdx.x;
  const int b = blockIdx.y;
  float corr[9];
  #pragma unroll
  for (int o = 0; o < 9; ++o) corr[o] = 0.f;
  #pragma unroll 2
  for (int c = 0; c < 32; ++c) {
    float xv = x[((size_t)b * 32 + c) * HW + p];
    const float* wp = warp + ((size_t)b * 288 + (size_t)c * 9) * HW + p;
    #pragma unroll
    for (int o = 0; o < 9; ++o) corr[o] += wp[(size_t)o * HW] * xv;
  }
  unsigned mask = 0;
  int packed = 0;
  #pragma unroll
  for (int t = 0; t < 3; ++t) {
    float best = -INFINITY; int bi = 0;
    #pragma unroll
    for (int o = 0; o < 9; ++o) {
      bool take = (((mask >> o) & 1u) == 0u) && (corr[o] > best);
      best = take ? corr[o] : best;
      bi   = take ? o       : bi;
    }
    mask   |= 1u << bi;
    packed |= bi << (4 * t);
  }
  idxo[(size_t)b * HW + p] = packed;
}

// ---------- gather selected warps + 3x3 conv with w_sel; out 32-ch NHWC f16 hi/lo ----------
__global__ __launch_bounds__(256)
void selconv_k(const float* __restrict__ warp, const int* __restrict__ idxp,
               const float* __restrict__ wsel, const float* __restrict__ bsel,
               _Float16* __restrict__ oH, _Float16* __restrict__ oL)
{
  const int tx = threadIdx.x & 31, ty = threadIdx.x >> 5;
  const int px = blockIdx.x * 32 + tx;
  const int py = blockIdx.y * 8 + ty;
  const int b  = blockIdx.z;

  int  nidx[9];
  bool nval[9];
  int  qoff[9];
  #pragma unroll
  for (int kh = 0; kh < 3; ++kh)
    #pragma unroll
    for (int kw = 0; kw < 3; ++kw) {
      int k = kh * 3 + kw;
      int qy = py + kh - 1, qx = px + kw - 1;
      nval[k] = (qy >= 0 && qy < H && qx >= 0 && qx < W);
      qoff[k] = qy * W + qx;
      nidx[k] = nval[k] ? idxp[(size_t)b * HW + qoff[k]] : 0;
    }

  float ws27[27];
  #pragma unroll
  for (int i = 0; i < 27; ++i) ws27[i] = wsel[i];
  const float bs = bsel[0];

  float arr[32];
  #pragma unroll 1
  for (int c = 0; c < 32; ++c) {
    float acc = bs;
    const float* wb = warp + ((size_t)b * 288 + (size_t)c * 9) * HW;
    #pragma unroll
    for (int k = 0; k < 9; ++k) {
      if (nval[k]) {
        int pk = nidx[k];
        #pragma unroll
        for (int t = 0; t < 3; ++t) {
          int o = (pk >> (4 * t)) & 15;
          acc += ws27[t * 9 + k] * wb[(size_t)o * HW + qoff[k]];
        }
      }
    }
    arr[c] = acc;
  }

  __attribute__((aligned(16))) _Float16 hv[32], lv[32];
  #pragma unroll
  for (int c = 0; c < 32; ++c) {
    _Float16 h = (_Float16)arr[c];
    hv[c] = h;
    lv[c] = (_Float16)((arr[c] - (float)h) * 2048.0f);
  }
  size_t ob = ((size_t)b * HW + (size_t)py * W + px) * 32;
  #pragma unroll
  for (int j = 0; j < 4; ++j) {
    *(half8v*)&oH[ob + j * 8] = *(half8v*)&hv[j * 8];
    *(half8v*)&oL[ob + j * 8] = *(half8v*)&lv[j * 8];
  }
}

// ---------- launch ----------
extern "C" void kernel_launch(void* const* d_in, const int* in_sizes, int n_in,
                              void* d_out, int out_size, void* d_ws, size_t ws_size,
                              hipStream_t stream) {
  const float* x      = (const float*)d_in[0];
  const float* key    = (const float*)d_in[1];
  const float* w_off1 = (const float*)d_in[2];
  const float* b_off1 = (const float*)d_in[3];
  const float* w_off2 = (const float*)d_in[4];
  const float* b_off2 = (const float*)d_in[5];
  const float* w_dcn  = (const float*)d_in[6];
  const float* b_dcn  = (const float*)d_in[7];
  const float* w_sel  = (const float*)d_in[8];
  const float* b_sel  = (const float*)d_in[9];
  const float* w_t1   = (const float*)d_in[10];
  const float* w_t2   = (const float*)d_in[11];
  const float* w_t3   = (const float*)d_in[12];
  const float* w_t4   = (const float*)d_in[13];
  const float* w_t5   = (const float*)d_in[14];

  // ---- workspace layout (peak ~185.2 MB; proven safe r5-r8) ----
  char* ws = (char*)d_ws;
  float* warp = (float*)(ws);                                // [2,288,HW] f32 NCHW, 144 MiB
  // pre-dcn scratch inside warp region (dead before dcn writes):
  _Float16* xH  = (_Float16*)(ws);                           // 8 MiB
  _Float16* xL  = (_Float16*)(ws + 8388608);
  _Float16* o1H = (_Float16*)(ws + 16777216);                // off1 out, 8+8 MiB
  _Float16* o1L = (_Float16*)(ws + 25165824);
  _Float16* w1H = (_Float16*)(ws + 33554432);                // off1/off2 weight tables
  _Float16* w1L = w1H + 18432;
  _Float16* w2H = w1L + 18432;
  _Float16* w2L = w2H + 9216;
  // outside warp region:
  _Float16* kH  = (_Float16*)(ws + 150994944);               // key pack, 8+8 MiB
  _Float16* kL  = (_Float16*)(ws + 159383552);
  _Float16* o2H = (_Float16*)(ws + 167772160);               // off2 out, 8+8 MiB
  _Float16* o2L = (_Float16*)(ws + 176160768);
  _Float16* wdH = (_Float16*)(ws + 184549376);               // dcn tables (165888 each)
  _Float16* wdL = wdH + 165888;                              // ends ~185.2 MB
  // post-dcn (kH/kL/o2H/o2L/wd regions become dead in stages):
  int*      idxb = (int*)(ws + 150994944);                   // 0.5 MiB (over kH, dead)
  _Float16* kwH  = (_Float16*)(ws + 159383552);              // selconv out (over kL)
  _Float16* kwL  = (_Float16*)(ws + 167772160);              //              (over o2H)
  _Float16* twB  = (_Float16*)(ws + 176160768);              // tail tables (over o2L)
  _Float16* t1H_w = twB;
  _Float16* t1L_w = twB + 9216;
  _Float16* t3H_w = twB + 18432;
  _Float16* t3L_w = twB + 165888;
  _Float16* t5H_w = twB + 313344;
  _Float16* t5L_w = twB + 322560;
  // tail activations inside dead warp region:
  float*    y1  = (float*)(ws);                              // t1 out NHWC f32 [2,HW,32], 16 MiB
  _Float16* t2H = (_Float16*)(ws + 16777216);                // chunked [2,4,HW,32], 32 MiB
  _Float16* t2L = (_Float16*)(ws + 50331648);                // 32 MiB
  float*    y3  = (float*)(ws + 83886080);                   // t3 out NHWC f32 [2,HW,128], 64 MiB
  _Float16* t4H = (_Float16*)(ws);                           // 8 MiB (y1 dead by then)
  _Float16* t4L = (_Float16*)(ws + 8388608);
  float* out = (float*)d_out;

  dim3 blk(256);

  // pack network inputs -> chunked f16 hi/lo
  pack_k<32><<<dim3(256, 2), blk, 0, stream>>>(x, xH, xL);
  pack_k<32><<<dim3(256, 2), blk, 0, stream>>>(key, kH, kL);
  // phase-1 weight tables
  prep_w_k<<<dim3(72),  blk, 0, stream>>>(w_off1, w1H, w1L, 32, 64);
  prep_w_k<<<dim3(36),  blk, 0, stream>>>(w_off2, w2H, w2L, 32, 32);
  prep_w_k<<<dim3(648), blk, 0, stream>>>(w_dcn,  wdH, wdL, 288, 64);

  // off1 = lrelu(conv(concat(x,key)))  -> f16 hi/lo     (grid = 512*nOc, 1-D)
  conv3x3_mfma_k<64, 32, 1, 1><<<dim3(512), blk, 0, stream>>>(
      xH, xL, kH, kL, 32, w1H, w1L, b_off1, nullptr, o1H, o1L);
  // off2 = lrelu(conv(off1))           -> f16 hi/lo
  conv3x3_mfma_k<32, 32, 1, 1><<<dim3(512), blk, 0, stream>>>(
      o1H, o1L, o1H, o1L, 32, w2H, w2L, b_off2, nullptr, o2H, o2L);
  // warp = conv(concat(key,off2))      -> NCHW f32 (feeds exact corr/top-k)
  conv3x3_mfma_k<64, 288, 0, 0><<<dim3(4608), blk, 0, stream>>>(
      kH, kL, o2H, o2L, 32, wdH, wdL, b_dcn, warp, nullptr, nullptr);
  // corr + top-3
  corr_topk_k<<<dim3(256, 2), blk, 0, stream>>>(warp, x, idxb);
  // key_warp -> f16 hi/lo (kwH/kwL)
  selconv_k<<<dim3(8, 32, 2), blk, 0, stream>>>(warp, idxb, w_sel, b_sel, kwH, kwL);

  // phase-2 weight tables
  prep_w_k<<<dim3(36),  blk, 0, stream>>>(w_t1, t1H_w, t1L_w, 32, 32);
  prep_w_k<<<dim3(576), blk, 0, stream>>>(w_t3, t3H_w, t3L_w, 128, 128);
  prep_w_k<<<dim3(36),  blk, 0, stream>>>(w_t5, t5H_w, t5L_w, 32, 32);

  // t1: conv3x3 (gelu) -> NHWC f32 y1
  conv3x3_mfma_k<32, 32, 2, 2><<<dim3(512), blk, 0, stream>>>(
      kwH, kwL, kwH, kwL, 32, t1H_w, t1L_w, nullptr, y1, nullptr, nullptr);
  // t2: 1x1 (gelu) -> chunked f16 [2,4,HW,32]
  conv1x1_nhwc_k<32, 16, 2><<<dim3(64, 2, 8), blk, 0, stream>>>(y1, w_t2, t2H, t2L, 128);
  // t3: conv3x3 (gelu) -> NHWC f32 y3
  conv3x3_mfma_k<128, 128, 2, 2><<<dim3(2048), blk, 0, stream>>>(
      t2H, t2L, t2H, t2L, 128, t3H_w, t3L_w, nullptr, y3, nullptr, nullptr);
  // t4: 1x1 (gelu) -> f16 hi/lo
  conv1x1_nhwc_k<128, 16, 2><<<dim3(64, 2, 2), blk, 0, stream>>>(y3, w_t4, t4H, t4L, 32);
  // t5: conv3x3 -> NCHW f32 final
  conv3x3_mfma_k<32, 32, 0, 0><<<dim3(512), blk, 0, stream>>>(
      t4H, t4L, t4H, t4L, 32, t5H_w, t5L_w, nullptr, out, nullptr, nullptr);
}

// Round 10
// 717.756 us; speedup vs baseline: 1.1235x; 1.1235x over previous
//
#include <hip/hip_runtime.h>
#include <math.h>

static constexpr int H = 256, W = 256, HW = H * W;

typedef __attribute__((ext_vector_type(8))) _Float16 half8v;  // 16B
typedef __attribute__((ext_vector_type(4))) _Float16 half4v;  // 8B
typedef __attribute__((ext_vector_type(4))) float  float4v;   // MFMA acc

// ---------- activations ----------
__device__ __forceinline__ float gelu_f(float v) {
  return 0.5f * v * (1.0f + erff(v * 0.70710678118654752440f));
}
template<int ACT>
__device__ __forceinline__ float apply_act(float v) {
  if constexpr (ACT == 1) return v >= 0.f ? v : 0.1f * v;   // LeakyReLU(0.1)
  if constexpr (ACT == 2) return gelu_f(v);
  return v;
}

// ---------- pack: NCHW f32 (C=32) -> chunked NHWC f16 hi + scaled lo ----------
template<int C>
__global__ __launch_bounds__(256)
void pack_k(const float* __restrict__ in, _Float16* __restrict__ hi, _Float16* __restrict__ lo)
{
  const int p = blockIdx.x * 256 + threadIdx.x;
  const int b = blockIdx.y;
  const float* ip = in + (size_t)b * C * HW + p;
  __attribute__((aligned(16))) _Float16 hv[C], lv[C];
  #pragma unroll
  for (int c = 0; c < C; ++c) {
    float v = ip[(size_t)c * HW];
    _Float16 h = (_Float16)v;
    hv[c] = h;
    lv[c] = (_Float16)((v - (float)h) * 2048.0f);
  }
  size_t ob = ((size_t)b * HW + p) * C;
  #pragma unroll
  for (int j = 0; j < C / 8; ++j) {
    *(half8v*)&hi[ob + j * 8] = *(half8v*)&hv[j * 8];
    *(half8v*)&lo[ob + j * 8] = *(half8v*)&lv[j * 8];
  }
}

// ---------- weight prep: [OC][CIN][3][3] f32 -> [tap][OC][CIN] f16 hi + scaled lo ----------
__global__ __launch_bounds__(256)
void prep_w_k(const float* __restrict__ w, _Float16* __restrict__ hi,
              _Float16* __restrict__ lo, int OC, int CIN)
{
  int tid = blockIdx.x * 256 + threadIdx.x;
  if (tid >= OC * CIN * 9) return;
  int ci = tid % CIN; int r = tid / CIN; int oc = r % OC; int tap = r / OC;
  float v = w[((size_t)oc * CIN + ci) * 9 + tap];
  _Float16 h = (_Float16)v;
  hi[tid] = h;
  lo[tid] = (_Float16)((v - (float)h) * 2048.0f);
}

// ---------- 3x3 conv, f16 MFMA; chunked-NHWC input ----------
// SPLIT=3: hi/lo split-3 (accP + accQ/2048), exact to ~2^-20 rel — pre-top-k path.
// SPLIT=1: single-f16 (accP only), hi planes only — tail path (post-top-k).
// OMODE: 0 = NCHW f32 out, 1 = NHWC f16 hi/lo out, 2 = NHWC f32 out.
// 1-D grid, XCD-grouped decode (bijective; grid%8==0): all oc-groups of a tile
// on one XCD at adjacent slots -> L2 reuse (r9: dcn FETCH 144->36 MB).
// LDS B-tile: [6 rows][66 px][REC halves], REC=64 (split-3: 4 hi + 4 lo
// granules, XOR class (g+4*lo)^(px&7)) or REC=32 (single: 4 granules,
// class (g^px)&3). Both: wave read/write covers contiguous 1KB -> conflict-free.
// MFMA 16x16x32 f16 (HW-verified r5-r9): A row=l&15 (oc), k=(l>>4)*8+j;
//   B col=l&15 (px); D col=l&15 (px), row=(l>>4)*4+reg (oc).
template<int CIN, int OC, int OCB, int ACT, int OMODE, int SPLIT>
__global__ __launch_bounds__(256)
void conv3x3_mfma_k(const _Float16* __restrict__ iH0, const _Float16* __restrict__ iL0,
                    const _Float16* __restrict__ iH1, const _Float16* __restrict__ iL1, int cin0,
                    const _Float16* __restrict__ wHi, const _Float16* __restrict__ wLo,
                    const float* __restrict__ bias,
                    float* __restrict__ outF, _Float16* __restrict__ oH, _Float16* __restrict__ oL)
{
  constexpr int NOF  = OCB / 16;
  constexpr int REC  = (SPLIT == 3) ? 64 : 32;
  constexpr int nOcg = OC / OCB;
  __shared__ _Float16 sB[6 * 66 * REC];

  const int l  = threadIdx.x & 63;
  const int wv = threadIdx.x >> 6;

  const int bid = blockIdx.x;
  const int xcd = bid & 7, q = bid >> 3;
  const int ocg  = q % nOcg;
  const int tIdx = (q / nOcg) * 8 + xcd;
  const int b   = tIdx >> 8;
  const int x0  = ((tIdx >> 6) & 3) * 64;
  const int y0  = (tIdx & 63) * 4;
  const int oc0 = ocg * OCB;

  float4v accP[NOF][4];
  float4v accQ[(SPLIT == 3) ? NOF : 1][4];
  #pragma unroll
  for (int j = 0; j < NOF; ++j)
    #pragma unroll
    for (int f = 0; f < 4; ++f) {
      accP[j][f] = (float4v){0.f, 0.f, 0.f, 0.f};
      if constexpr (SPLIT == 3) accQ[j][f] = (float4v){0.f, 0.f, 0.f, 0.f};
    }

  const int k8  = (l >> 4) * 8;
  const int ocl = l & 15;
  const int sq  = l & 3;          // ci granule (staging)
  const int spx = l >> 2;         // px offset within 16-px subtile (staging)

  #pragma unroll 1
  for (int cc = 0; cc < CIN; cc += 32) {
    // uniform chunk base
    const _Float16 *cbH, *cbL;
    if (cc < cin0) {
      size_t o = (size_t)(b * (cin0 >> 5) + (cc >> 5)) * HW * 32;
      cbH = iH0 + o; cbL = iL0 + o;
    } else {
      size_t o = (size_t)(b * ((CIN - cin0) >> 5) + ((cc - cin0) >> 5)) * HW * 32;
      cbH = iH1 + o; cbL = iL1 + o;
    }
    __syncthreads();
    if constexpr (SPLIT == 3) {
      // 60 wave-tasks = 6 rows x {hi,lo} x 5 px-subtiles
      #pragma unroll 2
      for (int t = wv; t < 60; t += 4) {
        int r = t / 10; int rem = t - r * 10; int bsel = rem / 5; int s = rem - bsel * 5;
        const _Float16* src = bsel ? cbL : cbH;
        int gy = y0 + r - 1;
        bool vy = (gy >= 0) && (gy < H);
        int gyc = gy < 0 ? 0 : (gy >= H ? H - 1 : gy);
        int pxl = s * 16 + spx;
        bool lact = (s < 4) || (l < 8);
        int gx = x0 + pxl - 1;
        bool vx = (gx >= 0) && (gx < W);
        int gxc = gx < 0 ? 0 : (gx >= W ? W - 1 : gx);
        half8v v;
        #pragma unroll
        for (int i = 0; i < 8; ++i) v[i] = (_Float16)0;
        if (lact && vy && vx)
          v = *(const half8v*)&src[((size_t)gyc * W + gxc) * 32 + sq * 8];
        int cls = (sq + (bsel ? 4 : 0)) ^ (pxl & 7);
        if (lact)
          *(half8v*)&sB[(r * 66 + pxl) * 64 + cls * 8] = v;
      }
    } else {
      // 30 wave-tasks = 6 rows x 5 px-subtiles (hi only)
      #pragma unroll 2
      for (int t = wv; t < 30; t += 4) {
        int r = t / 5; int s = t - r * 5;
        int gy = y0 + r - 1;
        bool vy = (gy >= 0) && (gy < H);
        int gyc = gy < 0 ? 0 : (gy >= H ? H - 1 : gy);
        int pxl = s * 16 + spx;
        bool lact = (s < 4) || (l < 8);
        int gx = x0 + pxl - 1;
        bool vx = (gx >= 0) && (gx < W);
        int gxc = gx < 0 ? 0 : (gx >= W ? W - 1 : gx);
        half8v v;
        #pragma unroll
        for (int i = 0; i < 8; ++i) v[i] = (_Float16)0;
        if (lact && vy && vx)
          v = *(const half8v*)&cbH[((size_t)gyc * W + gxc) * 32 + sq * 8];
        int cls = (sq ^ pxl) & 3;
        if (lact)
          *(half8v*)&sB[(r * 66 + pxl) * 32 + cls * 8] = v;
      }
    }
    __syncthreads();

    #pragma unroll 1
    for (int tap = 0; tap < 9; ++tap) {
      const int dy = tap / 3, dx = tap - 3 * (tap / 3);
      half8v ah[NOF], aq[(SPLIT == 3) ? NOF : 1];
      const _Float16* hp = wHi + ((size_t)tap * OC + oc0 + ocl) * CIN + cc + k8;
      #pragma unroll
      for (int j = 0; j < NOF; ++j)
        ah[j] = *(const half8v*)(hp + (size_t)j * 16 * CIN);
      if constexpr (SPLIT == 3) {
        const _Float16* lp = wLo + ((size_t)tap * OC + oc0 + ocl) * CIN + cc + k8;
        #pragma unroll
        for (int j = 0; j < NOF; ++j)
          aq[j] = *(const half8v*)(lp + (size_t)j * 16 * CIN);
      }
      const int px = ocl + dx;
      if constexpr (SPLIT == 3) {
        const int rbase = ((wv + dy) * 66 + px) * 64;
        const int clsH = (l >> 4) ^ (px & 7);
        const int clsQ = ((l >> 4) + 4) ^ (px & 7);
        #pragma unroll
        for (int f = 0; f < 4; ++f) {
          half8v bh = *(const half8v*)&sB[rbase + f * 1024 + clsH * 8];
          half8v bq = *(const half8v*)&sB[rbase + f * 1024 + clsQ * 8];
          #pragma unroll
          for (int j = 0; j < NOF; ++j) {
            accP[j][f] = __builtin_amdgcn_mfma_f32_16x16x32_f16(ah[j], bh, accP[j][f], 0, 0, 0);
            accQ[j][f] = __builtin_amdgcn_mfma_f32_16x16x32_f16(ah[j], bq, accQ[j][f], 0, 0, 0);
            accQ[j][f] = __builtin_amdgcn_mfma_f32_16x16x32_f16(aq[j], bh, accQ[j][f], 0, 0, 0);
          }
        }
      } else {
        const int rbase = ((wv + dy) * 66 + px) * 32;
        const int clsH = ((l >> 4) ^ px) & 3;
        #pragma unroll
        for (int f = 0; f < 4; ++f) {
          half8v bh = *(const half8v*)&sB[rbase + f * 512 + clsH * 8];
          #pragma unroll
          for (int j = 0; j < NOF; ++j)
            accP[j][f] = __builtin_amdgcn_mfma_f32_16x16x32_f16(ah[j], bh, accP[j][f], 0, 0, 0);
        }
      }
    }
  }

  // ---- epilogue: D col=l&15 (px), row=(l>>4)*4+reg (oc) ----
  #pragma unroll
  for (int j = 0; j < NOF; ++j)
    #pragma unroll
    for (int f = 0; f < 4; ++f) {
      const int px  = x0 + f * 16 + ocl;
      const int occ = oc0 + j * 16 + (l >> 4) * 4;
      float vv4[4];
      #pragma unroll
      for (int r = 0; r < 4; ++r) {
        float bv = bias ? bias[occ + r] : 0.f;
        float vv = accP[j][f][r] + bv;
        if constexpr (SPLIT == 3) vv += accQ[j][f][r] * (1.0f / 2048.0f);
        vv4[r] = apply_act<ACT>(vv);
      }
      if constexpr (OMODE == 0) {
        #pragma unroll
        for (int r = 0; r < 4; ++r)
          outF[((size_t)(b * OC + occ + r) * H + (y0 + wv)) * W + px] = vv4[r];
      } else if constexpr (OMODE == 1) {
        __attribute__((aligned(8))) _Float16 hv[4], lv[4];
        #pragma unroll
        for (int r = 0; r < 4; ++r) {
          _Float16 h = (_Float16)vv4[r];
          hv[r] = h;
          lv[r] = (_Float16)((vv4[r] - (float)h) * 2048.0f);
        }
        size_t ob = ((size_t)b * HW + (size_t)(y0 + wv) * W + px) * OC + occ;
        *(half4v*)&oH[ob] = *(half4v*)&hv[0];
        *(half4v*)&oL[ob] = *(half4v*)&lv[0];
      } else {
        float4 v4;
        v4.x = vv4[0]; v4.y = vv4[1]; v4.z = vv4[2]; v4.w = vv4[3];
        *(float4*)&outF[((size_t)b * HW + (size_t)(y0 + wv) * W + px) * OC + occ] = v4;
      }
    }
}

// ---------- 1x1 conv: NHWC f32 in -> chunked NHWC f16 out (hi only when !WLO) ----------
template<int CIN, int OCB, int ACT, bool WLO>
__global__ __launch_bounds__(256)
void conv1x1_nhwc_k(const float* __restrict__ in, const float* __restrict__ w,
                    _Float16* __restrict__ oH, _Float16* __restrict__ oL, int OC)
{
  __shared__ __align__(16) float sW[OCB][CIN];
  const int b   = blockIdx.y;
  const int oc0 = blockIdx.z * OCB;
  for (int t = threadIdx.x; t < OCB * CIN; t += 256)
    sW[t / CIN][t % CIN] = w[(size_t)(oc0 + t / CIN) * CIN + (t % CIN)];
  __syncthreads();

  const int pb = blockIdx.x * 1024 + threadIdx.x;    // 4 px at stride 256
  float acc[OCB][4];
  #pragma unroll
  for (int o = 0; o < OCB; ++o)
    #pragma unroll
    for (int i = 0; i < 4; ++i) acc[o][i] = 0.f;

  #pragma unroll 1
  for (int c0 = 0; c0 < CIN; c0 += 8) {
    float v[4][8];
    #pragma unroll
    for (int i = 0; i < 4; ++i) {
      const float* ip = in + ((size_t)b * HW + pb + i * 256) * CIN + c0;
      float4 a = *(const float4*)ip;
      float4 c = *(const float4*)(ip + 4);
      v[i][0]=a.x; v[i][1]=a.y; v[i][2]=a.z; v[i][3]=a.w;
      v[i][4]=c.x; v[i][5]=c.y; v[i][6]=c.z; v[i][7]=c.w;
    }
    #pragma unroll
    for (int o = 0; o < OCB; ++o) {
      const float4 w0 = *(const float4*)&sW[o][c0];
      const float4 w1 = *(const float4*)&sW[o][c0 + 4];
      #pragma unroll
      for (int i = 0; i < 4; ++i) {
        acc[o][i] += v[i][0]*w0.x + v[i][1]*w0.y + v[i][2]*w0.z + v[i][3]*w0.w
                   + v[i][4]*w1.x + v[i][5]*w1.y + v[i][6]*w1.z + v[i][7]*w1.w;
      }
    }
  }
  #pragma unroll
  for (int i = 0; i < 4; ++i) {
    __attribute__((aligned(16))) _Float16 hv[OCB], lv[OCB];
    #pragma unroll
    for (int o = 0; o < OCB; ++o) {
      float vv = apply_act<ACT>(acc[o][i]);
      _Float16 h = (_Float16)vv;
      hv[o] = h;
      if constexpr (WLO) lv[o] = (_Float16)((vv - (float)h) * 2048.0f);
    }
    size_t ob = ((size_t)(b * (OC >> 5) + (oc0 >> 5)) * HW + pb + i * 256) * 32 + (oc0 & 31);
    #pragma unroll
    for (int j = 0; j < OCB / 8; ++j) {
      *(half8v*)&oH[ob + j * 8] = *(half8v*)&hv[j * 8];
      if constexpr (WLO) *(half8v*)&oL[ob + j * 8] = *(half8v*)&lv[j * 8];
    }
  }
}

// ---------- corr + top-3 (jax tie-break: lower index wins); warp NCHW f32 ----------
__global__ __launch_bounds__(256)
void corr_topk_k(const float* __restrict__ warp, const float* __restrict__ x,
                 int* __restrict__ idxo)
{
  const int p = blockIdx.x * 256 + threadIdx.x;
  const int b = blockIdx.y;
  float corr[9];
  #pragma unroll
  for (int o = 0; o < 9; ++o) corr[o] = 0.f;
  #pragma unroll 2
  for (int c = 0; c < 32; ++c) {
    float xv = x[((size_t)b * 32 + c) * HW + p];
    const float* wp = warp + ((size_t)b * 288 + (size_t)c * 9) * HW + p;
    #pragma unroll
    for (int o = 0; o < 9; ++o) corr[o] += wp[(size_t)o * HW] * xv;
  }
  unsigned mask = 0;
  int packed = 0;
  #pragma unroll
  for (int t = 0; t < 3; ++t) {
    float best = -INFINITY; int bi = 0;
    #pragma unroll
    for (int o = 0; o < 9; ++o) {
      bool take = (((mask >> o) & 1u) == 0u) && (corr[o] > best);
      best = take ? corr[o] : best;
      bi   = take ? o       : bi;
    }
    mask   |= 1u << bi;
    packed |= bi << (4 * t);
  }
  idxo[(size_t)b * HW + p] = packed;
}

// ---------- gather selected warps + 3x3 conv with w_sel; out 32-ch NHWC f16 (hi only) ----------
__global__ __launch_bounds__(256)
void selconv_k(const float* __restrict__ warp, const int* __restrict__ idxp,
               const float* __restrict__ wsel, const float* __restrict__ bsel,
               _Float16* __restrict__ oH)
{
  const int tx = threadIdx.x & 31, ty = threadIdx.x >> 5;
  const int px = blockIdx.x * 32 + tx;
  const int py = blockIdx.y * 8 + ty;
  const int b  = blockIdx.z;

  int  nidx[9];
  bool nval[9];
  int  qoff[9];
  #pragma unroll
  for (int kh = 0; kh < 3; ++kh)
    #pragma unroll
    for (int kw = 0; kw < 3; ++kw) {
      int k = kh * 3 + kw;
      int qy = py + kh - 1, qx = px + kw - 1;
      nval[k] = (qy >= 0 && qy < H && qx >= 0 && qx < W);
      qoff[k] = qy * W + qx;
      nidx[k] = nval[k] ? idxp[(size_t)b * HW + qoff[k]] : 0;
    }

  float ws27[27];
  #pragma unroll
  for (int i = 0; i < 27; ++i) ws27[i] = wsel[i];
  const float bs = bsel[0];

  float arr[32];
  #pragma unroll 1
  for (int c = 0; c < 32; ++c) {
    float acc = bs;
    const float* wb = warp + ((size_t)b * 288 + (size_t)c * 9) * HW;
    #pragma unroll
    for (int k = 0; k < 9; ++k) {
      if (nval[k]) {
        int pk = nidx[k];
        #pragma unroll
        for (int t = 0; t < 3; ++t) {
          int o = (pk >> (4 * t)) & 15;
          acc += ws27[t * 9 + k] * wb[(size_t)o * HW + qoff[k]];
        }
      }
    }
    arr[c] = acc;
  }

  __attribute__((aligned(16))) _Float16 hv[32];
  #pragma unroll
  for (int c = 0; c < 32; ++c) hv[c] = (_Float16)arr[c];
  size_t ob = ((size_t)b * HW + (size_t)py * W + px) * 32;
  #pragma unroll
  for (int j = 0; j < 4; ++j)
    *(half8v*)&oH[ob + j * 8] = *(half8v*)&hv[j * 8];
}

// ---------- launch ----------
extern "C" void kernel_launch(void* const* d_in, const int* in_sizes, int n_in,
                              void* d_out, int out_size, void* d_ws, size_t ws_size,
                              hipStream_t stream) {
  const float* x      = (const float*)d_in[0];
  const float* key    = (const float*)d_in[1];
  const float* w_off1 = (const float*)d_in[2];
  const float* b_off1 = (const float*)d_in[3];
  const float* w_off2 = (const float*)d_in[4];
  const float* b_off2 = (const float*)d_in[5];
  const float* w_dcn  = (const float*)d_in[6];
  const float* b_dcn  = (const float*)d_in[7];
  const float* w_sel  = (const float*)d_in[8];
  const float* b_sel  = (const float*)d_in[9];
  const float* w_t1   = (const float*)d_in[10];
  const float* w_t2   = (const float*)d_in[11];
  const float* w_t3   = (const float*)d_in[12];
  const float* w_t4   = (const float*)d_in[13];
  const float* w_t5   = (const float*)d_in[14];

  // ---- workspace layout (peak ~185.2 MB; proven safe r5-r9) ----
  char* ws = (char*)d_ws;
  float* warp = (float*)(ws);                                // [2,288,HW] f32 NCHW, 144 MiB
  // pre-dcn scratch inside warp region (dead before dcn writes):
  _Float16* xH  = (_Float16*)(ws);                           // 8 MiB
  _Float16* xL  = (_Float16*)(ws + 8388608);
  _Float16* o1H = (_Float16*)(ws + 16777216);                // off1 out, 8+8 MiB
  _Float16* o1L = (_Float16*)(ws + 25165824);
  _Float16* w1H = (_Float16*)(ws + 33554432);                // off1/off2 weight tables
  _Float16* w1L = w1H + 18432;
  _Float16* w2H = w1L + 18432;
  _Float16* w2L = w2H + 9216;
  // outside warp region:
  _Float16* kH  = (_Float16*)(ws + 150994944);               // key pack, 8+8 MiB
  _Float16* kL  = (_Float16*)(ws + 159383552);
  _Float16* o2H = (_Float16*)(ws + 167772160);               // off2 out, 8+8 MiB
  _Float16* o2L = (_Float16*)(ws + 176160768);
  _Float16* wdH = (_Float16*)(ws + 184549376);               // dcn tables (165888 each)
  _Float16* wdL = wdH + 165888;                              // ends ~185.2 MB
  // post-dcn:
  int*      idxb = (int*)(ws + 150994944);                   // 0.5 MiB (over kH, dead)
  _Float16* kwH  = (_Float16*)(ws + 159383552);              // selconv out hi (over kL)
  _Float16* twB  = (_Float16*)(ws + 176160768);              // tail tables (over o2L)
  _Float16* t1H_w = twB;
  _Float16* t1L_w = twB + 9216;
  _Float16* t3H_w = twB + 18432;
  _Float16* t3L_w = twB + 165888;
  _Float16* t5H_w = twB + 313344;
  _Float16* t5L_w = twB + 322560;
  // tail activations inside dead warp region:
  float*    y1  = (float*)(ws);                              // t1 out NHWC f32 [2,HW,32], 16 MiB
  _Float16* t2H = (_Float16*)(ws + 16777216);                // chunked [2,4,HW,32], 32 MiB
  float*    y3  = (float*)(ws + 83886080);                   // t3 out NHWC f32 [2,HW,128], 64 MiB
  _Float16* t4H = (_Float16*)(ws + 50331648);                // 8 MiB (t2L's old slot, free)
  float* out = (float*)d_out;

  dim3 blk(256);

  // pack network inputs -> chunked f16 hi/lo
  pack_k<32><<<dim3(256, 2), blk, 0, stream>>>(x, xH, xL);
  pack_k<32><<<dim3(256, 2), blk, 0, stream>>>(key, kH, kL);
  // phase-1 weight tables
  prep_w_k<<<dim3(72),  blk, 0, stream>>>(w_off1, w1H, w1L, 32, 64);
  prep_w_k<<<dim3(36),  blk, 0, stream>>>(w_off2, w2H, w2L, 32, 32);
  prep_w_k<<<dim3(648), blk, 0, stream>>>(w_dcn,  wdH, wdL, 288, 64);

  // off1 = lrelu(conv(concat(x,key)))  -> f16 hi/lo   [split-3, pre-topk]
  conv3x3_mfma_k<64, 32, 32, 1, 1, 3><<<dim3(512), blk, 0, stream>>>(
      xH, xL, kH, kL, 32, w1H, w1L, b_off1, nullptr, o1H, o1L);
  // off2 = lrelu(conv(off1))           -> f16 hi/lo   [split-3]
  conv3x3_mfma_k<32, 32, 32, 1, 1, 3><<<dim3(512), blk, 0, stream>>>(
      o1H, o1L, o1H, o1L, 32, w2H, w2L, b_off2, nullptr, o2H, o2L);
  // warp = conv(concat(key,off2))      -> NCHW f32    [split-3, OCB=48]
  conv3x3_mfma_k<64, 288, 48, 0, 0, 3><<<dim3(3072), blk, 0, stream>>>(
      kH, kL, o2H, o2L, 32, wdH, wdL, b_dcn, warp, nullptr, nullptr);
  // corr + top-3
  corr_topk_k<<<dim3(256, 2), blk, 0, stream>>>(warp, x, idxb);
  // key_warp -> f16 hi (tail is single-f16; lo unused)
  selconv_k<<<dim3(8, 32, 2), blk, 0, stream>>>(warp, idxb, w_sel, b_sel, kwH);

  // phase-2 weight tables
  prep_w_k<<<dim3(36),  blk, 0, stream>>>(w_t1, t1H_w, t1L_w, 32, 32);
  prep_w_k<<<dim3(576), blk, 0, stream>>>(w_t3, t3H_w, t3L_w, 128, 128);
  prep_w_k<<<dim3(36),  blk, 0, stream>>>(w_t5, t5H_w, t5L_w, 32, 32);

  // t1: conv3x3 (gelu) -> NHWC f32 y1            [single-f16]
  conv3x3_mfma_k<32, 32, 32, 2, 2, 1><<<dim3(512), blk, 0, stream>>>(
      kwH, kwH, kwH, kwH, 32, t1H_w, t1L_w, nullptr, y1, nullptr, nullptr);
  // t2: 1x1 (gelu) -> chunked f16 hi [2,4,HW,32]
  conv1x1_nhwc_k<32, 16, 2, false><<<dim3(64, 2, 8), blk, 0, stream>>>(y1, w_t2, t2H, nullptr, 128);
  // t3: conv3x3 (gelu) -> NHWC f32 y3            [single-f16, OCB=64]
  conv3x3_mfma_k<128, 128, 64, 2, 2, 1><<<dim3(1024), blk, 0, stream>>>(
      t2H, t2H, t2H, t2H, 128, t3H_w, t3L_w, nullptr, y3, nullptr, nullptr);
  // t4: 1x1 (gelu) -> f16 hi
  conv1x1_nhwc_k<128, 16, 2, false><<<dim3(64, 2, 2), blk, 0, stream>>>(y3, w_t4, t4H, nullptr, 32);
  // t5: conv3x3 -> NCHW f32 final                [single-f16]
  conv3x3_mfma_k<32, 32, 32, 0, 0, 1><<<dim3(512), blk, 0, stream>>>(
      t4H, t4H, t4H, t4H, 32, t5H_w, t5L_w, nullptr, out, nullptr, nullptr);
}